// Round 1
// baseline (936.055 us; speedup 1.0000x reference)
//
#include <hip/hip_runtime.h>
#include <stdint.h>

// Problem constants (match reference)
#define T_TOK 8192
#define HID   1024
#define INTER 4096
#define NE    8
#define TOPK  2
#define CAP   2048            // min(ceil(T*K*CF/E), T) = 2048
#define EC    (NE * CAP)      // 16384 slots

// Workspace layout (bytes).
//  [0,   64MB)  WgT  bf16 (E, INTER, HID)   gate_w transposed
//  [64,  128MB) WuT  bf16 (E, INTER, HID)
//  [128, 192MB) WdT  bf16 (E, HID, INTER)   down_w transposed
//  [192, 224MB) Xe   bf16 (EC, HID)         gathered tokens
//  [224, 352MB) interB bf16 (EC, INTER)     silu(g)*u
//  [352, 384MB) pout bf16 (EC, HID)         permuted expert output
//  [416MB .. )  perm int (T,2), assign int (EC)

typedef __attribute__((ext_vector_type(8))) short bf16x8;
typedef __attribute__((ext_vector_type(4))) float f32x4;

static __device__ __forceinline__ unsigned short f2bf(float f) {
    union { float f; unsigned u; } a; a.f = f;
    unsigned r = a.u + 0x7FFFu + ((a.u >> 16) & 1u);   // round-nearest-even
    return (unsigned short)(r >> 16);
}
static __device__ __forceinline__ float bf2f(unsigned short b) {
    union { unsigned u; float f; } a; a.u = ((unsigned)b) << 16;
    return a.f;
}

static __device__ __forceinline__ void gload(const unsigned short* g, unsigned short* l) {
    // async global->LDS, 16B/lane; LDS dest = wave-uniform base + lane*16
    __builtin_amdgcn_global_load_lds((__attribute__((address_space(1))) void*)(uintptr_t)g,
                                     (__attribute__((address_space(3))) void*)l, 16, 0, 0);
}

// raw barrier with compiler-level memory fences (prevents IR/MIR motion of
// LDS ops across it; s_barrier intrinsic alone is not a memory fence)
#define BAR() do { asm volatile("" ::: "memory"); __builtin_amdgcn_s_barrier(); asm volatile("" ::: "memory"); } while (0)
// counted vmcnt wait (never drains the prefetch queue to 0 in the main loop)
#define WAITVM(N) asm volatile("s_waitcnt vmcnt(" #N ")" ::: "memory")

// ---------------------------------------------------------------- routing ---
__global__ __launch_bounds__(512) void route_kernel(const int* __restrict__ eidx,
                                                    int* __restrict__ perm,
                                                    int* __restrict__ assign) {
    int tid = threadIdx.x;
    for (int i = tid; i < EC; i += 512) assign[i] = 0;   // empty slot -> token 0
    __syncthreads();
    int e = tid >> 6;          // wave index == expert
    int lane = tid & 63;
    const int TPL = T_TOK / 64;                          // 128 tokens per lane
    int t0 = lane * TPL;
    int cnt = 0;
    for (int t = t0; t < t0 + TPL; ++t) {
        int e0 = eidx[t * 2], e1 = eidx[t * 2 + 1];
        cnt += (e0 == e) + (e1 == e);
    }
    int incl = cnt;
    #pragma unroll
    for (int off = 1; off < 64; off <<= 1) {
        int n = __shfl_up(incl, off, 64);
        if (lane >= off) incl += n;
    }
    int run = incl - cnt;
    for (int t = t0; t < t0 + TPL; ++t) {
        int e0 = eidx[t * 2], e1 = eidx[t * 2 + 1];
        int c = (e0 == e) + (e1 == e);
        if (c) {
            run += c;
            int pos = run;                       // inclusive (1-based)
            bool keep = (pos <= CAP);
            int pi = keep ? (pos + e * CAP) : 0;
            if (e0 == e) perm[t * 2]     = pi;
            if (e1 == e) perm[t * 2 + 1] = pi;
            if (keep) assign[pi - 1] = t;
        }
    }
}

// --------------------------------------------------- transpose + fp32->bf16 --
__global__ __launch_bounds__(256) void transpose_cvt(const float* __restrict__ in,
                                                     unsigned short* __restrict__ out,
                                                     int R, int Cc) {
    __shared__ unsigned short tile[64][68];
    int e = blockIdx.z;
    const float* inp = in + (size_t)e * R * Cc;
    unsigned short* outp = out + (size_t)e * R * Cc;
    int c0 = blockIdx.x * 64, r0 = blockIdx.y * 64;
    int t = threadIdx.x;
    int x = t & 15;
    int ry = t >> 4;
    #pragma unroll
    for (int j = 0; j < 4; ++j) {
        int row = ry + 16 * j;
        float4 v = *(const float4*)(inp + (size_t)(r0 + row) * Cc + c0 + 4 * x);
        ushort4 o;
        o.x = f2bf(v.x); o.y = f2bf(v.y); o.z = f2bf(v.z); o.w = f2bf(v.w);
        *(ushort4*)&tile[row][4 * x] = o;
    }
    __syncthreads();
    #pragma unroll
    for (int j = 0; j < 4; ++j) {
        int oc = ry + 16 * j;
        ushort4 o;
        o.x = tile[4 * x + 0][oc];
        o.y = tile[4 * x + 1][oc];
        o.z = tile[4 * x + 2][oc];
        o.w = tile[4 * x + 3][oc];
        *(ushort4*)(outp + (size_t)(c0 + oc) * R + r0 + 4 * x) = o;
    }
}

// ------------------------------------------------------- gather + cvt tokens -
__global__ __launch_bounds__(256) void gather_cvt(const float* __restrict__ hs,
                                                  const int* __restrict__ assign,
                                                  unsigned short* __restrict__ xe) {
    int s = blockIdx.x;
    int tok = assign[s];
    const float* src = hs + (size_t)tok * HID;
    unsigned short* dst = xe + (size_t)s * HID;
    int h = threadIdx.x * 4;
    float4 v = *(const float4*)(src + h);
    ushort4 o;
    o.x = f2bf(v.x); o.y = f2bf(v.y); o.z = f2bf(v.z); o.w = f2bf(v.w);
    *(ushort4*)(dst + h) = o;
}

// =============================================================================
// 8-phase 256-class GEMMs (T2 swizzle + T3/T4 counted-vmcnt pipeline + T5).
//
// Shared geometry: BM=256, BK=64, 512 threads = 8 waves (2M x 4N).
// LDS (dynamic, 128 KiB): 2 buffers x 32768 elems:
//   [0,8192)=AK0 (256r x 32c), [8192,16384)=AK1, [16384,24576)=B0 (128r x 64c),
//   [24576,32768)=B1.  Half-tile = 16KB = 2 global_load_lds per wave.
// Swizzle (conflict-balance, rule #21 both-sides): A rows (64B): chunk^=(r&3);
//   B rows (128B): chunk^=(r&7).  Writer pre-swizzles the GLOBAL source col so
//   the linear global_load_lds dest + swizzled ds_read agree.
// Phase schedule per K-tile t (consumes buf t&1, stages tile t+1):
//   P1: read AK0+B0(k0) | stage AK0',B0' | vmcnt(6) | bar | MFMA | bar
//   P2: read B1(k0)     | stage B1'      | vmcnt(6) | bar | MFMA | bar
//   P3: read AK1+B0(k1) | stage AK1'     |          | bar | MFMA | bar
//   P4: read B1(k1)     |                | vmcnt(4) | bar | MFMA | bar
// Every half-tile has exactly 3 phases of slack; queue never drains to 0.
// =============================================================================

// ------------------------------- fused gate+up GEMM + SiLU*mul (dual acc) ----
// B0 = gate panel (128 rows of WgT), B1 = up panel (128 rows of WuT).
__global__ __launch_bounds__(512, 2) void gateup_gemm(const unsigned short* __restrict__ Xe,
                                                      const unsigned short* __restrict__ WgT,
                                                      const unsigned short* __restrict__ WuT,
                                                      unsigned short* __restrict__ interB) {
    extern __shared__ __align__(16) unsigned short smemU[];
    const int K = HID;          // 1024
    const int NT = K / 64;      // 16 K-tiles

    // dispatch remap: expert = d&7 so each XCD (round-robin dispatch) works one
    // expert -> B panels / Xe slice stay in one XCD L2
    int d  = blockIdx.x + 8 * blockIdx.y + 256 * blockIdx.z;   // grid (8,32,8)
    int e  = d & 7;
    int m0 = ((d >> 3) & 7) * 256;
    int n0 = (d >> 6) * 128;

    int tid = threadIdx.x;
    int lane = tid & 63, w = tid >> 6;
    int lm = lane & 15, hi = lane >> 4;
    int wm = w >> 2, wn = w & 3;

    // swizzled reader offsets (elements within region)
    const int aRd  = (wm * 128 + lm) * 32 + ((hi ^ (lm & 3)) << 3);
    const int bRd0 = (wn * 32 + lm) * 64 + ((hi ^ (lm & 7)) << 3);
    const int bRd1 = (wn * 32 + lm) * 64 + (((4 + hi) ^ (lm & 7)) << 3);

    // stage sources (global col pre-swizzled to match linear LDS dest)
    int sAr = w * 32 + (lane >> 2);                       // rows, j=0 segment
    int sAc = ((lane & 3) ^ ((lane >> 2) & 3)) << 3;
    const unsigned short* aS0 = Xe + ((size_t)e * CAP + m0 + sAr) * K + sAc;
    const unsigned short* aS1 = aS0 + (size_t)16 * K;
    int sBr = w * 16 + (lane >> 3);
    int sBc = ((lane & 7) ^ ((lane >> 3) & 7)) << 3;
    const unsigned short* gS0 = WgT + ((size_t)e * INTER + n0 + sBr) * K + sBc;
    const unsigned short* gS1 = gS0 + (size_t)8 * K;
    const unsigned short* uS0 = WuT + ((size_t)e * INTER + n0 + sBr) * K + sBc;
    const unsigned short* uS1 = uS0 + (size_t)8 * K;

    const int dj0 = (w * 2 + 0) * 512;   // LDS dest (elems) within region
    const int dj1 = (w * 2 + 1) * 512;

    f32x4 zero = {0.f, 0.f, 0.f, 0.f};
    f32x4 accG[8][2], accU[8][2];
    #pragma unroll
    for (int i = 0; i < 8; ++i) {
        accG[i][0] = zero; accG[i][1] = zero;
        accU[i][0] = zero; accU[i][1] = zero;
    }

    // prologue: stage tile 0 into buf0, FIFO order AK0,B0,B1,AK1
    {
        unsigned short* wr = smemU;
        gload(aS0,      wr + dj0);          gload(aS1,      wr + dj1);
        gload(gS0,      wr + 16384 + dj0);  gload(gS1,      wr + 16384 + dj1);
        gload(uS0,      wr + 24576 + dj0);  gload(uS1,      wr + 24576 + dj1);
        gload(aS0 + 32, wr + 8192 + dj0);   gload(aS1 + 32, wr + 8192 + dj1);
        WAITVM(4);              // retire AK0,B0; leave B1,AK1 in flight
        BAR();
    }

    bf16x8 aF[8];

    for (int t = 0; t < NT - 1; ++t) {
        const unsigned short* rd = smemU + (t & 1) * 32768;
        unsigned short* wr = smemU + ((t + 1) & 1) * 32768;
        const int gk = (t + 1) * 64;
        // ---- P1: A(k0) x gate
        #pragma unroll
        for (int mi = 0; mi < 8; ++mi) aF[mi] = *(const bf16x8*)(rd + aRd + mi * 512);
        bf16x8 b0 = *(const bf16x8*)(rd + 16384 + bRd0);
        bf16x8 b1 = *(const bf16x8*)(rd + 16384 + bRd0 + 1024);
        gload(aS0 + gk, wr + dj0);          gload(aS1 + gk, wr + dj1);
        gload(gS0 + gk, wr + 16384 + dj0);  gload(gS1 + gk, wr + 16384 + dj1);
        WAITVM(6);
        BAR();
        __builtin_amdgcn_s_setprio(1);
        #pragma unroll
        for (int mi = 0; mi < 8; ++mi) {
            accG[mi][0] = __builtin_amdgcn_mfma_f32_16x16x32_bf16(aF[mi], b0, accG[mi][0], 0, 0, 0);
            accG[mi][1] = __builtin_amdgcn_mfma_f32_16x16x32_bf16(aF[mi], b1, accG[mi][1], 0, 0, 0);
        }
        __builtin_amdgcn_s_setprio(0);
        BAR();
        // ---- P2: A(k0) x up
        b0 = *(const bf16x8*)(rd + 24576 + bRd0);
        b1 = *(const bf16x8*)(rd + 24576 + bRd0 + 1024);
        gload(uS0 + gk, wr + 24576 + dj0);  gload(uS1 + gk, wr + 24576 + dj1);
        WAITVM(6);
        BAR();
        __builtin_amdgcn_s_setprio(1);
        #pragma unroll
        for (int mi = 0; mi < 8; ++mi) {
            accU[mi][0] = __builtin_amdgcn_mfma_f32_16x16x32_bf16(aF[mi], b0, accU[mi][0], 0, 0, 0);
            accU[mi][1] = __builtin_amdgcn_mfma_f32_16x16x32_bf16(aF[mi], b1, accU[mi][1], 0, 0, 0);
        }
        __builtin_amdgcn_s_setprio(0);
        BAR();
        // ---- P3: A(k1) x gate
        #pragma unroll
        for (int mi = 0; mi < 8; ++mi) aF[mi] = *(const bf16x8*)(rd + 8192 + aRd + mi * 512);
        b0 = *(const bf16x8*)(rd + 16384 + bRd1);
        b1 = *(const bf16x8*)(rd + 16384 + bRd1 + 1024);
        gload(aS0 + gk + 32, wr + 8192 + dj0);  gload(aS1 + gk + 32, wr + 8192 + dj1);
        BAR();
        __builtin_amdgcn_s_setprio(1);
        #pragma unroll
        for (int mi = 0; mi < 8; ++mi) {
            accG[mi][0] = __builtin_amdgcn_mfma_f32_16x16x32_bf16(aF[mi], b0, accG[mi][0], 0, 0, 0);
            accG[mi][1] = __builtin_amdgcn_mfma_f32_16x16x32_bf16(aF[mi], b1, accG[mi][1], 0, 0, 0);
        }
        __builtin_amdgcn_s_setprio(0);
        BAR();
        // ---- P4: A(k1) x up
        b0 = *(const bf16x8*)(rd + 24576 + bRd1);
        b1 = *(const bf16x8*)(rd + 24576 + bRd1 + 1024);
        WAITVM(4);
        BAR();
        __builtin_amdgcn_s_setprio(1);
        #pragma unroll
        for (int mi = 0; mi < 8; ++mi) {
            accU[mi][0] = __builtin_amdgcn_mfma_f32_16x16x32_bf16(aF[mi], b0, accU[mi][0], 0, 0, 0);
            accU[mi][1] = __builtin_amdgcn_mfma_f32_16x16x32_bf16(aF[mi], b1, accU[mi][1], 0, 0, 0);
        }
        __builtin_amdgcn_s_setprio(0);
        BAR();
    }
    // peeled last tile (no stages; drain waits 2/0)
    {
        const unsigned short* rd = smemU + ((NT - 1) & 1) * 32768;
        #pragma unroll
        for (int mi = 0; mi < 8; ++mi) aF[mi] = *(const bf16x8*)(rd + aRd + mi * 512);
        bf16x8 b0 = *(const bf16x8*)(rd + 16384 + bRd0);
        bf16x8 b1 = *(const bf16x8*)(rd + 16384 + bRd0 + 1024);
        WAITVM(2);
        BAR();
        #pragma unroll
        for (int mi = 0; mi < 8; ++mi) {
            accG[mi][0] = __builtin_amdgcn_mfma_f32_16x16x32_bf16(aF[mi], b0, accG[mi][0], 0, 0, 0);
            accG[mi][1] = __builtin_amdgcn_mfma_f32_16x16x32_bf16(aF[mi], b1, accG[mi][1], 0, 0, 0);
        }
        BAR();
        b0 = *(const bf16x8*)(rd + 24576 + bRd0);
        b1 = *(const bf16x8*)(rd + 24576 + bRd0 + 1024);
        WAITVM(0);
        BAR();
        #pragma unroll
        for (int mi = 0; mi < 8; ++mi) {
            accU[mi][0] = __builtin_amdgcn_mfma_f32_16x16x32_bf16(aF[mi], b0, accU[mi][0], 0, 0, 0);
            accU[mi][1] = __builtin_amdgcn_mfma_f32_16x16x32_bf16(aF[mi], b1, accU[mi][1], 0, 0, 0);
        }
        BAR();
        #pragma unroll
        for (int mi = 0; mi < 8; ++mi) aF[mi] = *(const bf16x8*)(rd + 8192 + aRd + mi * 512);
        b0 = *(const bf16x8*)(rd + 16384 + bRd1);
        b1 = *(const bf16x8*)(rd + 16384 + bRd1 + 1024);
        BAR();
        #pragma unroll
        for (int mi = 0; mi < 8; ++mi) {
            accG[mi][0] = __builtin_amdgcn_mfma_f32_16x16x32_bf16(aF[mi], b0, accG[mi][0], 0, 0, 0);
            accG[mi][1] = __builtin_amdgcn_mfma_f32_16x16x32_bf16(aF[mi], b1, accG[mi][1], 0, 0, 0);
        }
        BAR();
        b0 = *(const bf16x8*)(rd + 24576 + bRd1);
        b1 = *(const bf16x8*)(rd + 24576 + bRd1 + 1024);
        BAR();
        #pragma unroll
        for (int mi = 0; mi < 8; ++mi) {
            accU[mi][0] = __builtin_amdgcn_mfma_f32_16x16x32_bf16(aF[mi], b0, accU[mi][0], 0, 0, 0);
            accU[mi][1] = __builtin_amdgcn_mfma_f32_16x16x32_bf16(aF[mi], b1, accU[mi][1], 0, 0, 0);
        }
        BAR();
    }

    // epilogue: silu(G)*U -> bounce [256][136] -> vector global stores
    unsigned short* bounce = smemU;
    #pragma unroll
    for (int mi = 0; mi < 8; ++mi)
        #pragma unroll
        for (int nf = 0; nf < 2; ++nf) {
            f32x4 g4 = accG[mi][nf], u4 = accU[mi][nf];
            #pragma unroll
            for (int r = 0; r < 4; ++r) {
                int row = wm * 128 + mi * 16 + hi * 4 + r;
                int col = wn * 32 + nf * 16 + lm;
                float g = g4[r];
                float s = g / (1.f + __expf(-g)) * u4[r];
                bounce[row * 136 + col] = f2bf(s);
            }
        }
    __syncthreads();
    {
        unsigned short* Op = interB + ((size_t)e * CAP + m0) * INTER + n0;
        int rr = tid >> 1, cb = (tid & 1) * 64;
        #pragma unroll
        for (int j = 0; j < 8; ++j) {
            bf16x8 v = *(const bf16x8*)&bounce[rr * 136 + cb + j * 8];
            *(bf16x8*)(Op + (size_t)rr * INTER + cb + j * 8) = v;
        }
    }
}

// ------------------------------------------------------------- down GEMM ----
// 256x256 tile; B0 = WdT rows [n0,n0+128), B1 = [n0+128,n0+256).
__global__ __launch_bounds__(512, 2) void down_gemm(const unsigned short* __restrict__ interB,
                                                    const unsigned short* __restrict__ WdT,
                                                    unsigned short* __restrict__ pout) {
    extern __shared__ __align__(16) unsigned short smemU[];
    const int K = INTER;        // 4096
    const int NT = K / 64;      // 64 K-tiles

    int d  = blockIdx.x + 8 * blockIdx.y + 32 * blockIdx.z;   // grid (8,4,8)
    int e  = d & 7;
    int r5 = d >> 3;
    int m0 = (r5 & 7) * 256;
    int n0 = (r5 >> 3) * 256;

    int tid = threadIdx.x;
    int lane = tid & 63, w = tid >> 6;
    int lm = lane & 15, hi = lane >> 4;
    int wm = w >> 2, wn = w & 3;

    const int aRd  = (wm * 128 + lm) * 32 + ((hi ^ (lm & 3)) << 3);
    const int bRd0 = (wn * 32 + lm) * 64 + ((hi ^ (lm & 7)) << 3);
    const int bRd1 = (wn * 32 + lm) * 64 + (((4 + hi) ^ (lm & 7)) << 3);

    int sAr = w * 32 + (lane >> 2);
    int sAc = ((lane & 3) ^ ((lane >> 2) & 3)) << 3;
    const unsigned short* aS0 = interB + ((size_t)e * CAP + m0 + sAr) * K + sAc;
    const unsigned short* aS1 = aS0 + (size_t)16 * K;
    int sBr = w * 16 + (lane >> 3);
    int sBc = ((lane & 7) ^ ((lane >> 3) & 7)) << 3;
    const unsigned short* b0S0 = WdT + ((size_t)e * HID + n0 + sBr) * K + sBc;
    const unsigned short* b0S1 = b0S0 + (size_t)8 * K;
    const unsigned short* b1S0 = b0S0 + (size_t)128 * K;
    const unsigned short* b1S1 = b1S0 + (size_t)8 * K;

    const int dj0 = (w * 2 + 0) * 512;
    const int dj1 = (w * 2 + 1) * 512;

    f32x4 zero = {0.f, 0.f, 0.f, 0.f};
    f32x4 acc[8][4];
    #pragma unroll
    for (int i = 0; i < 8; ++i)
        #pragma unroll
        for (int j = 0; j < 4; ++j) acc[i][j] = zero;

    {
        unsigned short* wr = smemU;
        gload(aS0,      wr + dj0);          gload(aS1,      wr + dj1);
        gload(b0S0,     wr + 16384 + dj0);  gload(b0S1,     wr + 16384 + dj1);
        gload(b1S0,     wr + 24576 + dj0);  gload(b1S1,     wr + 24576 + dj1);
        gload(aS0 + 32, wr + 8192 + dj0);   gload(aS1 + 32, wr + 8192 + dj1);
        WAITVM(4);
        BAR();
    }

    bf16x8 aF[8];

    for (int t = 0; t < NT - 1; ++t) {
        const unsigned short* rd = smemU + (t & 1) * 32768;
        unsigned short* wr = smemU + ((t + 1) & 1) * 32768;
        const int gk = (t + 1) * 64;
        // ---- P1: A(k0) x B0
        #pragma unroll
        for (int mi = 0; mi < 8; ++mi) aF[mi] = *(const bf16x8*)(rd + aRd + mi * 512);
        bf16x8 b0 = *(const bf16x8*)(rd + 16384 + bRd0);
        bf16x8 b1 = *(const bf16x8*)(rd + 16384 + bRd0 + 1024);
        gload(aS0 + gk, wr + dj0);           gload(aS1 + gk, wr + dj1);
        gload(b0S0 + gk, wr + 16384 + dj0);  gload(b0S1 + gk, wr + 16384 + dj1);
        WAITVM(6);
        BAR();
        __builtin_amdgcn_s_setprio(1);
        #pragma unroll
        for (int mi = 0; mi < 8; ++mi) {
            acc[mi][0] = __builtin_amdgcn_mfma_f32_16x16x32_bf16(aF[mi], b0, acc[mi][0], 0, 0, 0);
            acc[mi][1] = __builtin_amdgcn_mfma_f32_16x16x32_bf16(aF[mi], b1, acc[mi][1], 0, 0, 0);
        }
        __builtin_amdgcn_s_setprio(0);
        BAR();
        // ---- P2: A(k0) x B1
        b0 = *(const bf16x8*)(rd + 24576 + bRd0);
        b1 = *(const bf16x8*)(rd + 24576 + bRd0 + 1024);
        gload(b1S0 + gk, wr + 24576 + dj0);  gload(b1S1 + gk, wr + 24576 + dj1);
        WAITVM(6);
        BAR();
        __builtin_amdgcn_s_setprio(1);
        #pragma unroll
        for (int mi = 0; mi < 8; ++mi) {
            acc[mi][2] = __builtin_amdgcn_mfma_f32_16x16x32_bf16(aF[mi], b0, acc[mi][2], 0, 0, 0);
            acc[mi][3] = __builtin_amdgcn_mfma_f32_16x16x32_bf16(aF[mi], b1, acc[mi][3], 0, 0, 0);
        }
        __builtin_amdgcn_s_setprio(0);
        BAR();
        // ---- P3: A(k1) x B0
        #pragma unroll
        for (int mi = 0; mi < 8; ++mi) aF[mi] = *(const bf16x8*)(rd + 8192 + aRd + mi * 512);
        b0 = *(const bf16x8*)(rd + 16384 + bRd1);
        b1 = *(const bf16x8*)(rd + 16384 + bRd1 + 1024);
        gload(aS0 + gk + 32, wr + 8192 + dj0);  gload(aS1 + gk + 32, wr + 8192 + dj1);
        BAR();
        __builtin_amdgcn_s_setprio(1);
        #pragma unroll
        for (int mi = 0; mi < 8; ++mi) {
            acc[mi][0] = __builtin_amdgcn_mfma_f32_16x16x32_bf16(aF[mi], b0, acc[mi][0], 0, 0, 0);
            acc[mi][1] = __builtin_amdgcn_mfma_f32_16x16x32_bf16(aF[mi], b1, acc[mi][1], 0, 0, 0);
        }
        __builtin_amdgcn_s_setprio(0);
        BAR();
        // ---- P4: A(k1) x B1
        b0 = *(const bf16x8*)(rd + 24576 + bRd1);
        b1 = *(const bf16x8*)(rd + 24576 + bRd1 + 1024);
        WAITVM(4);
        BAR();
        __builtin_amdgcn_s_setprio(1);
        #pragma unroll
        for (int mi = 0; mi < 8; ++mi) {
            acc[mi][2] = __builtin_amdgcn_mfma_f32_16x16x32_bf16(aF[mi], b0, acc[mi][2], 0, 0, 0);
            acc[mi][3] = __builtin_amdgcn_mfma_f32_16x16x32_bf16(aF[mi], b1, acc[mi][3], 0, 0, 0);
        }
        __builtin_amdgcn_s_setprio(0);
        BAR();
    }
    // peeled last tile
    {
        const unsigned short* rd = smemU + ((NT - 1) & 1) * 32768;
        #pragma unroll
        for (int mi = 0; mi < 8; ++mi) aF[mi] = *(const bf16x8*)(rd + aRd + mi * 512);
        bf16x8 b0 = *(const bf16x8*)(rd + 16384 + bRd0);
        bf16x8 b1 = *(const bf16x8*)(rd + 16384 + bRd0 + 1024);
        WAITVM(2);
        BAR();
        #pragma unroll
        for (int mi = 0; mi < 8; ++mi) {
            acc[mi][0] = __builtin_amdgcn_mfma_f32_16x16x32_bf16(aF[mi], b0, acc[mi][0], 0, 0, 0);
            acc[mi][1] = __builtin_amdgcn_mfma_f32_16x16x32_bf16(aF[mi], b1, acc[mi][1], 0, 0, 0);
        }
        BAR();
        b0 = *(const bf16x8*)(rd + 24576 + bRd0);
        b1 = *(const bf16x8*)(rd + 24576 + bRd0 + 1024);
        WAITVM(0);
        BAR();
        #pragma unroll
        for (int mi = 0; mi < 8; ++mi) {
            acc[mi][2] = __builtin_amdgcn_mfma_f32_16x16x32_bf16(aF[mi], b0, acc[mi][2], 0, 0, 0);
            acc[mi][3] = __builtin_amdgcn_mfma_f32_16x16x32_bf16(aF[mi], b1, acc[mi][3], 0, 0, 0);
        }
        BAR();
        #pragma unroll
        for (int mi = 0; mi < 8; ++mi) aF[mi] = *(const bf16x8*)(rd + 8192 + aRd + mi * 512);
        b0 = *(const bf16x8*)(rd + 16384 + bRd1);
        b1 = *(const bf16x8*)(rd + 16384 + bRd1 + 1024);
        BAR();
        #pragma unroll
        for (int mi = 0; mi < 8; ++mi) {
            acc[mi][0] = __builtin_amdgcn_mfma_f32_16x16x32_bf16(aF[mi], b0, acc[mi][0], 0, 0, 0);
            acc[mi][1] = __builtin_amdgcn_mfma_f32_16x16x32_bf16(aF[mi], b1, acc[mi][1], 0, 0, 0);
        }
        BAR();
        b0 = *(const bf16x8*)(rd + 24576 + bRd1);
        b1 = *(const bf16x8*)(rd + 24576 + bRd1 + 1024);
        BAR();
        #pragma unroll
        for (int mi = 0; mi < 8; ++mi) {
            acc[mi][2] = __builtin_amdgcn_mfma_f32_16x16x32_bf16(aF[mi], b0, acc[mi][2], 0, 0, 0);
            acc[mi][3] = __builtin_amdgcn_mfma_f32_16x16x32_bf16(aF[mi], b1, acc[mi][3], 0, 0, 0);
        }
        BAR();
    }

    // epilogue: two bounce rounds (cols [n0,n0+128), [n0+128,n0+256))
    unsigned short* bounce = smemU;
    int rr = tid >> 1, cb = (tid & 1) * 64;
    // round 0
    #pragma unroll
    for (int mi = 0; mi < 8; ++mi)
        #pragma unroll
        for (int nfh = 0; nfh < 2; ++nfh) {
            f32x4 a4 = acc[mi][nfh];
            #pragma unroll
            for (int r = 0; r < 4; ++r)
                bounce[(wm * 128 + mi * 16 + hi * 4 + r) * 136 + wn * 32 + nfh * 16 + lm] = f2bf(a4[r]);
        }
    __syncthreads();
    {
        unsigned short* Op = pout + ((size_t)e * CAP + m0) * HID + n0;
        #pragma unroll
        for (int j = 0; j < 8; ++j) {
            bf16x8 v = *(const bf16x8*)&bounce[rr * 136 + cb + j * 8];
            *(bf16x8*)(Op + (size_t)rr * HID + cb + j * 8) = v;
        }
    }
    __syncthreads();
    // round 1
    #pragma unroll
    for (int mi = 0; mi < 8; ++mi)
        #pragma unroll
        for (int nfh = 0; nfh < 2; ++nfh) {
            f32x4 a4 = acc[mi][2 + nfh];
            #pragma unroll
            for (int r = 0; r < 4; ++r)
                bounce[(wm * 128 + mi * 16 + hi * 4 + r) * 136 + wn * 32 + nfh * 16 + lm] = f2bf(a4[r]);
        }
    __syncthreads();
    {
        unsigned short* Op = pout + ((size_t)e * CAP + m0) * HID + n0 + 128;
        #pragma unroll
        for (int j = 0; j < 8; ++j) {
            bf16x8 v = *(const bf16x8*)&bounce[rr * 136 + cb + j * 8];
            *(bf16x8*)(Op + (size_t)rr * HID + cb + j * 8) = v;
        }
    }
}

// --------------------------------------------------------------- combine ----
__global__ __launch_bounds__(256) void combine_kernel(const float* __restrict__ aff,
                                                      const int* __restrict__ eidx,
                                                      const int* __restrict__ perm,
                                                      const unsigned short* __restrict__ pout,
                                                      float* __restrict__ out) {
    int t = blockIdx.x;
    int e0 = eidx[t * 2], e1 = eidx[t * 2 + 1];
    int p0 = perm[t * 2], p1 = perm[t * 2 + 1];
    bool k0 = p0 > 0, k1 = p1 > 0;
    float a0 = aff[t * NE + e0], a1 = aff[t * NE + e1];
    float denom = (k0 ? fabsf(a0) : 0.f) + ((e1 != e0 && k1) ? fabsf(a1) : 0.f);
    denom = fmaxf(denom, 1e-12f);
    float w0 = k0 ? a0 / denom : 0.f;
    float w1 = k1 ? a1 / denom : 0.f;
    int s0 = k0 ? p0 - 1 : 0;
    int s1 = k1 ? p1 - 1 : 0;
    int h = threadIdx.x * 4;
    ushort4 v0 = *(const ushort4*)(pout + (size_t)s0 * HID + h);
    ushort4 v1 = *(const ushort4*)(pout + (size_t)s1 * HID + h);
    float4 o;
    o.x = w0 * bf2f(v0.x) + w1 * bf2f(v1.x);
    o.y = w0 * bf2f(v0.y) + w1 * bf2f(v1.y);
    o.z = w0 * bf2f(v0.z) + w1 * bf2f(v1.z);
    o.w = w0 * bf2f(v0.w) + w1 * bf2f(v1.w);
    *(float4*)(out + (size_t)t * HID + h) = o;
}

// ----------------------------------------------------------------- launch ---
extern "C" void kernel_launch(void* const* d_in, const int* in_sizes, int n_in,
                              void* d_out, int out_size, void* d_ws, size_t ws_size,
                              hipStream_t stream) {
    const float* hs   = (const float*)d_in[0];   // (T, HID)
    const float* aff  = (const float*)d_in[1];   // (T, NE)
    const float* gw   = (const float*)d_in[2];   // (NE, HID, INTER)
    const float* uw   = (const float*)d_in[3];   // (NE, HID, INTER)
    const float* dw   = (const float*)d_in[4];   // (NE, INTER, HID)
    const int*   eidx = (const int*)d_in[5];     // (T, TOPK)
    float* out = (float*)d_out;

    char* ws = (char*)d_ws;
    unsigned short* WgT    = (unsigned short*)(ws);
    unsigned short* WuT    = (unsigned short*)(ws + ((size_t)64  << 20));
    unsigned short* WdT    = (unsigned short*)(ws + ((size_t)128 << 20));
    unsigned short* Xe     = (unsigned short*)(ws + ((size_t)192 << 20));
    unsigned short* interB = (unsigned short*)(ws + ((size_t)224 << 20));
    unsigned short* pout   = (unsigned short*)(ws + ((size_t)352 << 20));
    int*            perm   = (int*)           (ws + ((size_t)416 << 20));
    int*            assign = perm + (T_TOK * TOPK);

    static int attr_set = 0;
    if (!attr_set) {
        (void)hipFuncSetAttribute((const void*)gateup_gemm,
                                  hipFuncAttributeMaxDynamicSharedMemorySize, 131072);
        (void)hipFuncSetAttribute((const void*)down_gemm,
                                  hipFuncAttributeMaxDynamicSharedMemorySize, 131072);
        attr_set = 1;
    }

    route_kernel<<<1, 512, 0, stream>>>(eidx, perm, assign);
    transpose_cvt<<<dim3(INTER / 64, HID / 64, NE), 256, 0, stream>>>(uw, WuT, HID, INTER);
    transpose_cvt<<<dim3(INTER / 64, HID / 64, NE), 256, 0, stream>>>(gw, WgT, HID, INTER);
    gather_cvt<<<EC, 256, 0, stream>>>(hs, assign, Xe);
    gateup_gemm<<<dim3(8, 32, 8), 512, 131072, stream>>>(Xe, WgT, WuT, interB);
    transpose_cvt<<<dim3(HID / 64, INTER / 64, NE), 256, 0, stream>>>(dw, WdT, INTER, HID);
    down_gemm<<<dim3(8, 4, 8), 512, 131072, stream>>>(interB, WdT, pout);
    combine_kernel<<<T_TOK, 256, 0, stream>>>(aff, eidx, perm, pout, out);
}

// Round 2
// 912.028 us; speedup vs baseline: 1.0263x; 1.0263x over previous
//
#include <hip/hip_runtime.h>
#include <stdint.h>

// Problem constants (match reference)
#define T_TOK 8192
#define HID   1024
#define INTER 4096
#define NE    8
#define TOPK  2
#define CAP   2048            // min(ceil(T*K*CF/E), T) = 2048
#define EC    (NE * CAP)      // 16384 slots

// Workspace layout (bytes).
//  [0,   64MB)  WgT  bf16 (E, INTER, HID)   gate_w transposed
//  [64,  128MB) WuT  bf16 (E, INTER, HID)
//  [128, 192MB) WdT  bf16 (E, HID, INTER)   down_w transposed
//  [192, 224MB) Xe   bf16 (EC, HID)         gathered tokens
//  [224, 352MB) interB bf16 (EC, INTER)     silu(g)*u
//  [352, 384MB) pout bf16 (EC, HID)         permuted expert output
//  [416MB .. )  perm int (T,2), assign int (EC)

typedef __attribute__((ext_vector_type(8))) short bf16x8;
typedef __attribute__((ext_vector_type(4))) float f32x4;

static __device__ __forceinline__ unsigned short f2bf(float f) {
    union { float f; unsigned u; } a; a.f = f;
    unsigned r = a.u + 0x7FFFu + ((a.u >> 16) & 1u);   // round-nearest-even
    return (unsigned short)(r >> 16);
}
static __device__ __forceinline__ float bf2f(unsigned short b) {
    union { unsigned u; float f; } a; a.u = ((unsigned)b) << 16;
    return a.f;
}

static __device__ __forceinline__ void gload(const unsigned short* g, unsigned short* l) {
    // async global->LDS, 16B/lane; LDS dest = wave-uniform base + lane*16
    __builtin_amdgcn_global_load_lds((__attribute__((address_space(1))) void*)(uintptr_t)g,
                                     (__attribute__((address_space(3))) void*)l, 16, 0, 0);
}

#define BAR() do { asm volatile("" ::: "memory"); __builtin_amdgcn_s_barrier(); asm volatile("" ::: "memory"); } while (0)
#define WAITVM(N) asm volatile("s_waitcnt vmcnt(" #N ")" ::: "memory")

// ---------------------------------------------------------------- routing ---
__global__ __launch_bounds__(512) void route_kernel(const int* __restrict__ eidx,
                                                    int* __restrict__ perm,
                                                    int* __restrict__ assign) {
    int tid = threadIdx.x;
    for (int i = tid; i < EC; i += 512) assign[i] = 0;   // empty slot -> token 0
    __syncthreads();
    int e = tid >> 6;          // wave index == expert
    int lane = tid & 63;
    const int TPL = T_TOK / 64;                          // 128 tokens per lane
    int t0 = lane * TPL;
    int cnt = 0;
    for (int t = t0; t < t0 + TPL; ++t) {
        int e0 = eidx[t * 2], e1 = eidx[t * 2 + 1];
        cnt += (e0 == e) + (e1 == e);
    }
    int incl = cnt;
    #pragma unroll
    for (int off = 1; off < 64; off <<= 1) {
        int n = __shfl_up(incl, off, 64);
        if (lane >= off) incl += n;
    }
    int run = incl - cnt;
    for (int t = t0; t < t0 + TPL; ++t) {
        int e0 = eidx[t * 2], e1 = eidx[t * 2 + 1];
        int c = (e0 == e) + (e1 == e);
        if (c) {
            run += c;
            int pos = run;                       // inclusive (1-based)
            bool keep = (pos <= CAP);
            int pi = keep ? (pos + e * CAP) : 0;
            if (e0 == e) perm[t * 2]     = pi;
            if (e1 == e) perm[t * 2 + 1] = pi;
            if (keep) assign[pi - 1] = t;
        }
    }
}

// --------------------------------------------------- transpose + fp32->bf16 --
// merged gw+uw transpose: z<8 -> (in0,out0), else (in1,out1). R=HID, C=INTER.
__global__ __launch_bounds__(256) void transpose_cvt2(const float* __restrict__ in0,
                                                      unsigned short* __restrict__ out0,
                                                      const float* __restrict__ in1,
                                                      unsigned short* __restrict__ out1) {
    __shared__ unsigned short tile[64][68];
    int z = blockIdx.z;
    const float* in = (z < 8) ? in0 : in1;
    unsigned short* out = (z < 8) ? out0 : out1;
    int e = z & 7;
    const int R = HID, Cc = INTER;
    const float* inp = in + (size_t)e * R * Cc;
    unsigned short* outp = out + (size_t)e * R * Cc;
    int c0 = blockIdx.x * 64, r0 = blockIdx.y * 64;
    int t = threadIdx.x;
    int x = t & 15;
    int ry = t >> 4;
    #pragma unroll
    for (int j = 0; j < 4; ++j) {
        int row = ry + 16 * j;
        float4 v = *(const float4*)(inp + (size_t)(r0 + row) * Cc + c0 + 4 * x);
        ushort4 o;
        o.x = f2bf(v.x); o.y = f2bf(v.y); o.z = f2bf(v.z); o.w = f2bf(v.w);
        *(ushort4*)&tile[row][4 * x] = o;
    }
    __syncthreads();
    #pragma unroll
    for (int j = 0; j < 4; ++j) {
        int oc = ry + 16 * j;
        ushort4 o;
        o.x = tile[4 * x + 0][oc];
        o.y = tile[4 * x + 1][oc];
        o.z = tile[4 * x + 2][oc];
        o.w = tile[4 * x + 3][oc];
        *(ushort4*)(outp + (size_t)(c0 + oc) * R + r0 + 4 * x) = o;
    }
}

__global__ __launch_bounds__(256) void transpose_cvt(const float* __restrict__ in,
                                                     unsigned short* __restrict__ out,
                                                     int R, int Cc) {
    __shared__ unsigned short tile[64][68];
    int e = blockIdx.z;
    const float* inp = in + (size_t)e * R * Cc;
    unsigned short* outp = out + (size_t)e * R * Cc;
    int c0 = blockIdx.x * 64, r0 = blockIdx.y * 64;
    int t = threadIdx.x;
    int x = t & 15;
    int ry = t >> 4;
    #pragma unroll
    for (int j = 0; j < 4; ++j) {
        int row = ry + 16 * j;
        float4 v = *(const float4*)(inp + (size_t)(r0 + row) * Cc + c0 + 4 * x);
        ushort4 o;
        o.x = f2bf(v.x); o.y = f2bf(v.y); o.z = f2bf(v.z); o.w = f2bf(v.w);
        *(ushort4*)&tile[row][4 * x] = o;
    }
    __syncthreads();
    #pragma unroll
    for (int j = 0; j < 4; ++j) {
        int oc = ry + 16 * j;
        ushort4 o;
        o.x = tile[4 * x + 0][oc];
        o.y = tile[4 * x + 1][oc];
        o.z = tile[4 * x + 2][oc];
        o.w = tile[4 * x + 3][oc];
        *(ushort4*)(outp + (size_t)(c0 + oc) * R + r0 + 4 * x) = o;
    }
}

// ------------------------------------------------------- gather + cvt tokens -
__global__ __launch_bounds__(256) void gather_cvt(const float* __restrict__ hs,
                                                  const int* __restrict__ assign,
                                                  unsigned short* __restrict__ xe) {
    int s = blockIdx.x;
    int tok = assign[s];
    const float* src = hs + (size_t)tok * HID;
    unsigned short* dst = xe + (size_t)s * HID;
    int h = threadIdx.x * 4;
    float4 v = *(const float4*)(src + h);
    ushort4 o;
    o.x = f2bf(v.x); o.y = f2bf(v.y); o.z = f2bf(v.z); o.w = f2bf(v.w);
    *(ushort4*)(dst + h) = o;
}

// =============================================================================
// 2-block/CU GEMMs. 256 threads = 4 waves (2M x 2N); BM=256, BK=32.
// Triple-buffered LDS, 72 KiB/block -> 2 blocks/CU (144 KiB) -> 4 waves/SIMD
// across TWO INDEPENDENT barrier groups: one block's MFMA phase overlaps the
// other's ds_read/stage phase (m114 co-scheduling).
//
// Per buffer (12288 elems = 24 KiB): A [0,8192) = 256r x 32k;
//   R1 [8192,10240) = 64r x 32k; R2 [10240,12288) = 64r x 32k.
//   gateup: R1 = gate panel (N=64), R2 = up panel.
//   down:   R1 = B rows {wn*64+[0,32)}, R2 = B rows {wn*64+[32,64)} (N=128).
// Swizzle (64B rows, 4 chunks of 16B): chunk ^= (row>>1)&3 — uses the bank-base
//   parity bit so each quarter-wave spreads 2-per-bank (free, m136). Writer
//   pre-swizzles the GLOBAL column (rule #21); LDS dest stays linear.
// Per K-tile (32): P1 {read aF x8 + R1 x2 | stage A'(4)+R1'(1) | vmcnt(11) |
//   bar | 16 MFMA | bar}; P2 {read R2 x2 | stage R2'(1) | vmcnt(7) | bar |
//   16 MFMA | bar}. Stages target tile t+2 (triple buffer) -> ~4 phases slack.
// =============================================================================

#define BUFE 12288

#define MFMA16(ACC, O, B0, B1) \
    _Pragma("unroll") \
    for (int mi = 0; mi < 8; ++mi) { \
        ACC[mi][O]     = __builtin_amdgcn_mfma_f32_16x16x32_bf16(aF[mi], B0, ACC[mi][O], 0, 0, 0); \
        ACC[mi][O + 1] = __builtin_amdgcn_mfma_f32_16x16x32_bf16(aF[mi], B1, ACC[mi][O + 1], 0, 0, 0); \
    }

#define LOAD_AF(rd) \
    _Pragma("unroll") \
    for (int mi = 0; mi < 8; ++mi) aF[mi] = *(const bf16x8*)((rd) + aRd + mi * 512);

// ------------------------------- fused gate+up GEMM + SiLU*mul (dual acc) ----
__global__ __launch_bounds__(256, 2) void gateup_gemm(const unsigned short* __restrict__ Xe,
                                                      const unsigned short* __restrict__ WgT,
                                                      const unsigned short* __restrict__ WuT,
                                                      unsigned short* __restrict__ interB) {
    extern __shared__ __align__(16) unsigned short smemU[];
    const int K = HID;          // 1024
    const int NT = K / 32;      // 32 K-tiles

    int e  = blockIdx.x;                 // x fastest -> XCD-pinned per expert
    int m0 = blockIdx.y * 256;
    int n0 = blockIdx.z * 64;

    int tid = threadIdx.x;
    int lane = tid & 63, w = tid >> 6;
    int lm = lane & 15, hi = lane >> 4;
    int wm = w >> 1, wn = w & 1;

    const int swz  = (hi ^ ((lm >> 1) & 3)) << 3;
    const int aRd  = (wm * 128 + lm) * 32 + swz;
    const int r1Rd = 8192  + (wn * 32 + lm) * 32 + swz;
    const int r2Rd = 10240 + (wn * 32 + lm) * 32 + swz;

    int sr = lane >> 2;
    int sc = ((lane & 3) ^ ((lane >> 3) & 3)) << 3;   // pre-swizzled global col
    const unsigned short* aS = Xe  + ((size_t)e * CAP   + m0 + w * 64 + sr) * K + sc;
    const unsigned short* gS = WgT + ((size_t)e * INTER + n0 + w * 16 + sr) * K + sc;
    const unsigned short* uS = WuT + ((size_t)e * INTER + n0 + w * 16 + sr) * K + sc;
    const int dA = w * 2048;           // + j*512
    const int dG = 8192  + w * 512;
    const int dU = 10240 + w * 512;

    f32x4 zero = {0.f, 0.f, 0.f, 0.f};
    f32x4 accG[8][2], accU[8][2];
    #pragma unroll
    for (int i = 0; i < 8; ++i) {
        accG[i][0] = zero; accG[i][1] = zero;
        accU[i][0] = zero; accU[i][1] = zero;
    }

    unsigned short* p0 = smemU;
    unsigned short* p1 = smemU + BUFE;
    unsigned short* p2 = smemU + 2 * BUFE;

    // prologue: stage tiles 0 (buf0) and 1 (buf1); FIFO [A*4,G,U] x2
    {
        #pragma unroll
        for (int j = 0; j < 4; ++j) gload(aS + (size_t)j * 16 * K, p0 + dA + j * 512);
        gload(gS, p0 + dG); gload(uS, p0 + dU);
        #pragma unroll
        for (int j = 0; j < 4; ++j) gload(aS + (size_t)j * 16 * K + 32, p1 + dA + j * 512);
        gload(gS + 32, p1 + dG); gload(uS + 32, p1 + dU);
        WAITVM(7);             // retire A0*4,G0; keep [U0, A1*4, G1, U1]
        BAR();
    }

    bf16x8 aF[8];
    int gk = 64;
    for (int t = 0; t < NT - 2; ++t) {
        const unsigned short* rd = p0;
        unsigned short* wr = p2;
        // ---- P1: A x gate
        LOAD_AF(rd);
        bf16x8 b0 = *(const bf16x8*)(rd + r1Rd);
        bf16x8 b1 = *(const bf16x8*)(rd + r1Rd + 512);
        #pragma unroll
        for (int j = 0; j < 4; ++j) gload(aS + (size_t)j * 16 * K + gk, wr + dA + j * 512);
        gload(gS + gk, wr + dG);
        WAITVM(11);
        BAR();
        __builtin_amdgcn_s_setprio(1);
        MFMA16(accG, 0, b0, b1);
        __builtin_amdgcn_s_setprio(0);
        BAR();
        // ---- P2: A x up
        b0 = *(const bf16x8*)(rd + r2Rd);
        b1 = *(const bf16x8*)(rd + r2Rd + 512);
        gload(uS + gk, wr + dU);
        WAITVM(7);
        BAR();
        __builtin_amdgcn_s_setprio(1);
        MFMA16(accU, 0, b0, b1);
        __builtin_amdgcn_s_setprio(0);
        BAR();
        // rotate buffers
        unsigned short* tmp = p0; p0 = p1; p1 = p2; p2 = tmp;
        gk += 32;
    }
    // ---- peeled tile NT-2 (no stages; waits 6,1)
    {
        const unsigned short* rd = p0;
        LOAD_AF(rd);
        bf16x8 b0 = *(const bf16x8*)(rd + r1Rd);
        bf16x8 b1 = *(const bf16x8*)(rd + r1Rd + 512);
        WAITVM(6);
        BAR();
        MFMA16(accG, 0, b0, b1);
        BAR();
        b0 = *(const bf16x8*)(rd + r2Rd);
        b1 = *(const bf16x8*)(rd + r2Rd + 512);
        WAITVM(1);
        BAR();
        MFMA16(accU, 0, b0, b1);
        BAR();
    }
    // ---- peeled tile NT-1 (waits 0)
    {
        const unsigned short* rd = p1;
        LOAD_AF(rd);
        bf16x8 b0 = *(const bf16x8*)(rd + r1Rd);
        bf16x8 b1 = *(const bf16x8*)(rd + r1Rd + 512);
        WAITVM(0);
        BAR();
        MFMA16(accG, 0, b0, b1);
        BAR();
        b0 = *(const bf16x8*)(rd + r2Rd);
        b1 = *(const bf16x8*)(rd + r2Rd + 512);
        MFMA16(accU, 0, b0, b1);
    }

    // epilogue: silu(G)*U -> bounce [256][72] -> vector stores (row = 128B seg)
    __syncthreads();
    unsigned short* bounce = smemU;
    #pragma unroll
    for (int mi = 0; mi < 8; ++mi)
        #pragma unroll
        for (int nf = 0; nf < 2; ++nf) {
            f32x4 g4 = accG[mi][nf], u4 = accU[mi][nf];
            #pragma unroll
            for (int r = 0; r < 4; ++r) {
                int row = wm * 128 + mi * 16 + hi * 4 + r;
                int col = wn * 32 + nf * 16 + lm;
                float g = g4[r];
                float s = g / (1.f + __expf(-g)) * u4[r];
                bounce[row * 72 + col] = f2bf(s);
            }
        }
    __syncthreads();
    {
        unsigned short* Op = interB + ((size_t)e * CAP + m0) * INTER + n0;
        int rr = tid >> 3, cc = (tid & 7) * 8;
        #pragma unroll
        for (int j = 0; j < 8; ++j) {
            int row = rr + 32 * j;
            bf16x8 v = *(const bf16x8*)&bounce[row * 72 + cc];
            *(bf16x8*)(Op + (size_t)row * INTER + cc) = v;
        }
    }
}

// ------------------------------------------------------------- down GEMM ----
__global__ __launch_bounds__(256, 2) void down_gemm(const unsigned short* __restrict__ interB,
                                                    const unsigned short* __restrict__ WdT,
                                                    unsigned short* __restrict__ pout) {
    extern __shared__ __align__(16) unsigned short smemU[];
    const int K = INTER;        // 4096
    const int NT = K / 32;      // 128 K-tiles

    int e  = blockIdx.x;
    int m0 = blockIdx.y * 256;
    int n0 = blockIdx.z * 128;

    int tid = threadIdx.x;
    int lane = tid & 63, w = tid >> 6;
    int lm = lane & 15, hi = lane >> 4;
    int wm = w >> 1, wn = w & 1;

    const int swz  = (hi ^ ((lm >> 1) & 3)) << 3;
    const int aRd  = (wm * 128 + lm) * 32 + swz;
    const int r1Rd = 8192  + (wn * 32 + lm) * 32 + swz;
    const int r2Rd = 10240 + (wn * 32 + lm) * 32 + swz;

    int sr = lane >> 2;
    int sc = ((lane & 3) ^ ((lane >> 3) & 3)) << 3;
    const unsigned short* aS = interB + ((size_t)e * CAP + m0 + w * 64 + sr) * K + sc;
    int rb1 = (w >> 1) * 64 + (w & 1) * 16;       // R1 LDS rows w*16.. map here
    const unsigned short* b1S = WdT + ((size_t)e * HID + n0 + rb1 + sr) * K + sc;
    const unsigned short* b2S = WdT + ((size_t)e * HID + n0 + rb1 + 32 + sr) * K + sc;
    const int dA = w * 2048;
    const int d1 = 8192  + w * 512;
    const int d2 = 10240 + w * 512;

    f32x4 zero = {0.f, 0.f, 0.f, 0.f};
    f32x4 acc[8][4];
    #pragma unroll
    for (int i = 0; i < 8; ++i)
        #pragma unroll
        for (int j = 0; j < 4; ++j) acc[i][j] = zero;

    unsigned short* p0 = smemU;
    unsigned short* p1 = smemU + BUFE;
    unsigned short* p2 = smemU + 2 * BUFE;

    {
        #pragma unroll
        for (int j = 0; j < 4; ++j) gload(aS + (size_t)j * 16 * K, p0 + dA + j * 512);
        gload(b1S, p0 + d1); gload(b2S, p0 + d2);
        #pragma unroll
        for (int j = 0; j < 4; ++j) gload(aS + (size_t)j * 16 * K + 32, p1 + dA + j * 512);
        gload(b1S + 32, p1 + d1); gload(b2S + 32, p1 + d2);
        WAITVM(7);
        BAR();
    }

    bf16x8 aF[8];
    int gk = 64;
    for (int t = 0; t < NT - 2; ++t) {
        const unsigned short* rd = p0;
        unsigned short* wr = p2;
        // ---- P1: A x B(ni 0,1)
        LOAD_AF(rd);
        bf16x8 b0 = *(const bf16x8*)(rd + r1Rd);
        bf16x8 b1 = *(const bf16x8*)(rd + r1Rd + 512);
        #pragma unroll
        for (int j = 0; j < 4; ++j) gload(aS + (size_t)j * 16 * K + gk, wr + dA + j * 512);
        gload(b1S + gk, wr + d1);
        WAITVM(11);
        BAR();
        __builtin_amdgcn_s_setprio(1);
        MFMA16(acc, 0, b0, b1);
        __builtin_amdgcn_s_setprio(0);
        BAR();
        // ---- P2: A x B(ni 2,3)
        b0 = *(const bf16x8*)(rd + r2Rd);
        b1 = *(const bf16x8*)(rd + r2Rd + 512);
        gload(b2S + gk, wr + d2);
        WAITVM(7);
        BAR();
        __builtin_amdgcn_s_setprio(1);
        MFMA16(acc, 2, b0, b1);
        __builtin_amdgcn_s_setprio(0);
        BAR();
        unsigned short* tmp = p0; p0 = p1; p1 = p2; p2 = tmp;
        gk += 32;
    }
    {   // peeled NT-2
        const unsigned short* rd = p0;
        LOAD_AF(rd);
        bf16x8 b0 = *(const bf16x8*)(rd + r1Rd);
        bf16x8 b1 = *(const bf16x8*)(rd + r1Rd + 512);
        WAITVM(6);
        BAR();
        MFMA16(acc, 0, b0, b1);
        BAR();
        b0 = *(const bf16x8*)(rd + r2Rd);
        b1 = *(const bf16x8*)(rd + r2Rd + 512);
        WAITVM(1);
        BAR();
        MFMA16(acc, 2, b0, b1);
        BAR();
    }
    {   // peeled NT-1
        const unsigned short* rd = p1;
        LOAD_AF(rd);
        bf16x8 b0 = *(const bf16x8*)(rd + r1Rd);
        bf16x8 b1 = *(const bf16x8*)(rd + r1Rd + 512);
        WAITVM(0);
        BAR();
        MFMA16(acc, 0, b0, b1);
        BAR();
        b0 = *(const bf16x8*)(rd + r2Rd);
        b1 = *(const bf16x8*)(rd + r2Rd + 512);
        MFMA16(acc, 2, b0, b1);
    }

    // epilogue: two bounce rounds; round R covers cols wn*64 + R*32 + [0,32)
    unsigned short* bounce = smemU;
    unsigned short* Op = pout + ((size_t)e * CAP + m0) * HID + n0;
    int rr = tid >> 3, c8 = tid & 7;
    int colp = c8 * 8;
    #pragma unroll
    for (int R = 0; R < 2; ++R) {
        __syncthreads();
        #pragma unroll
        for (int mi = 0; mi < 8; ++mi)
            #pragma unroll
            for (int nf = 0; nf < 2; ++nf) {
                f32x4 a4 = acc[mi][2 * R + nf];
                #pragma unroll
                for (int r = 0; r < 4; ++r) {
                    int row = wm * 128 + mi * 16 + hi * 4 + r;
                    int col = wn * 32 + nf * 16 + lm;   // compacted col'
                    bounce[row * 72 + col] = f2bf(a4[r]);
                }
            }
        __syncthreads();
        int gcol = (colp >> 5) * 64 + R * 32 + (colp & 31);
        #pragma unroll
        for (int j = 0; j < 8; ++j) {
            int row = rr + 32 * j;
            bf16x8 v = *(const bf16x8*)&bounce[row * 72 + colp];
            *(bf16x8*)(Op + (size_t)row * HID + gcol) = v;
        }
    }
}

// --------------------------------------------------------------- combine ----
__global__ __launch_bounds__(256) void combine_kernel(const float* __restrict__ aff,
                                                      const int* __restrict__ eidx,
                                                      const int* __restrict__ perm,
                                                      const unsigned short* __restrict__ pout,
                                                      float* __restrict__ out) {
    int t = blockIdx.x;
    int e0 = eidx[t * 2], e1 = eidx[t * 2 + 1];
    int p0 = perm[t * 2], p1 = perm[t * 2 + 1];
    bool k0 = p0 > 0, k1 = p1 > 0;
    float a0 = aff[t * NE + e0], a1 = aff[t * NE + e1];
    float denom = (k0 ? fabsf(a0) : 0.f) + ((e1 != e0 && k1) ? fabsf(a1) : 0.f);
    denom = fmaxf(denom, 1e-12f);
    float w0 = k0 ? a0 / denom : 0.f;
    float w1 = k1 ? a1 / denom : 0.f;
    int s0 = k0 ? p0 - 1 : 0;
    int s1 = k1 ? p1 - 1 : 0;
    int h = threadIdx.x * 4;
    ushort4 v0 = *(const ushort4*)(pout + (size_t)s0 * HID + h);
    ushort4 v1 = *(const ushort4*)(pout + (size_t)s1 * HID + h);
    float4 o;
    o.x = w0 * bf2f(v0.x) + w1 * bf2f(v1.x);
    o.y = w0 * bf2f(v0.y) + w1 * bf2f(v1.y);
    o.z = w0 * bf2f(v0.z) + w1 * bf2f(v1.z);
    o.w = w0 * bf2f(v0.w) + w1 * bf2f(v1.w);
    *(float4*)(out + (size_t)t * HID + h) = o;
}

// ----------------------------------------------------------------- launch ---
extern "C" void kernel_launch(void* const* d_in, const int* in_sizes, int n_in,
                              void* d_out, int out_size, void* d_ws, size_t ws_size,
                              hipStream_t stream) {
    (void)in_sizes; (void)n_in; (void)out_size; (void)ws_size;
    const float* hs   = (const float*)d_in[0];   // (T, HID)
    const float* aff  = (const float*)d_in[1];   // (T, NE)
    const float* gw   = (const float*)d_in[2];   // (NE, HID, INTER)
    const float* uw   = (const float*)d_in[3];   // (NE, HID, INTER)
    const float* dw   = (const float*)d_in[4];   // (NE, INTER, HID)
    const int*   eidx = (const int*)d_in[5];     // (T, TOPK)
    float* out = (float*)d_out;

    char* ws = (char*)d_ws;
    unsigned short* WgT    = (unsigned short*)(ws);
    unsigned short* WuT    = (unsigned short*)(ws + ((size_t)64  << 20));
    unsigned short* WdT    = (unsigned short*)(ws + ((size_t)128 << 20));
    unsigned short* Xe     = (unsigned short*)(ws + ((size_t)192 << 20));
    unsigned short* interB = (unsigned short*)(ws + ((size_t)224 << 20));
    unsigned short* pout   = (unsigned short*)(ws + ((size_t)352 << 20));
    int*            perm   = (int*)           (ws + ((size_t)416 << 20));
    int*            assign = perm + (T_TOK * TOPK);

    static int attr_set = 0;
    if (!attr_set) {
        (void)hipFuncSetAttribute((const void*)gateup_gemm,
                                  hipFuncAttributeMaxDynamicSharedMemorySize, 73728);
        (void)hipFuncSetAttribute((const void*)down_gemm,
                                  hipFuncAttributeMaxDynamicSharedMemorySize, 73728);
        attr_set = 1;
    }

    route_kernel<<<1, 512, 0, stream>>>(eidx, perm, assign);
    transpose_cvt2<<<dim3(INTER / 64, HID / 64, 16), 256, 0, stream>>>(uw, WuT, gw, WgT);
    transpose_cvt<<<dim3(HID / 64, INTER / 64, NE), 256, 0, stream>>>(dw, WdT, INTER, HID);
    gather_cvt<<<EC, 256, 0, stream>>>(hs, assign, Xe);
    gateup_gemm<<<dim3(8, 8, 64), 256, 73728, stream>>>(Xe, WgT, WuT, interB);
    down_gemm<<<dim3(8, 8, 8), 256, 73728, stream>>>(interB, WdT, pout);
    combine_kernel<<<T_TOK, 256, 0, stream>>>(aff, eidx, perm, pout, out);
}